// Round 12
// baseline (130.702 us; speedup 1.0000x reference)
//
#include <hip/hip_runtime.h>
#include <hip/hip_bf16.h>
#include <stdint.h>

// Single attention head. B=4, T=2048, C=1024, H=64. FP32 in/out (proven).
// Outputs concat fp32: out[B,T,H], k[B,T,H], v[B,T,H]. scale = 1/32.
//
// R12 = R11 with final latency trims:
//  - qkv: A-fragments loaded DIRECTLY from global x (two float4/lane/step,
//    16 fully-consumed 128B lines per wave-step) -> no LDS, no barrier,
//    waves fully independent.
//  - attn: heavy-first block order (qt = 127 - blockIdx.x) to shrink the
//    causal-imbalance tail.
// ws (4 MB): [0) Wb 384KB; [1MB) qb; [2MB) kb; [3MB) vT (1MB each, bf16).

#define NB 4
#define TT 2048
#define CC 1024
#define HH 64
#define NKV (NB * TT * HH)

typedef __attribute__((ext_vector_type(8))) short short8; // 8 bf16 = 4 VGPRs
typedef __attribute__((ext_vector_type(4))) float f32x4;  // MFMA C/D

__device__ __forceinline__ unsigned short f2bf(float f) {
    union { float f; unsigned int i; } v;
    v.f = f;
    unsigned int r = v.i + 0x7fffu + ((v.i >> 16) & 1u); // RNE
    return (unsigned short)(r >> 16);
}
// packed RNE f32x2 -> bf16x2 (v_cvt_pk_bf16_f32 on gfx950)
__device__ __forceinline__ unsigned int pkbf2(float a, float b) {
    __hip_bfloat162 h = __float22bfloat162_rn(make_float2(a, b));
    union { __hip_bfloat162 h; unsigned int u; } c;
    c.h = h;
    return c.u;
}

// ---------------------------------------------------------------------------
// prep_wb (proven): Wb[((s*32+kk)*64 + l)*8 + j] =
// W_m[k = 32kk + (l>>4)*8 + j][h = (s&3)*16 + (l&15)], m = s>>2.
// ---------------------------------------------------------------------------
__global__ __launch_bounds__(256) void prep_wb(const float* __restrict__ Wq,
                                               const float* __restrict__ Wk,
                                               const float* __restrict__ Wv,
                                               unsigned short* __restrict__ Wb) {
    int gid = blockIdx.x * 256 + threadIdx.x; // 0 .. 196607
    int j  = gid & 7;
    int l  = (gid >> 3) & 63;
    int kk = (gid >> 9) & 31;
    int s  = gid >> 14;
    int k  = kk * 32 + (l >> 4) * 8 + j;
    int h  = (s & 3) * 16 + (l & 15);
    const float* W = (s >> 2) == 0 ? Wq : (s >> 2) == 1 ? Wk : Wv;
    Wb[gid] = f2bf(W[(size_t)k * HH + h]);
}

// ---------------------------------------------------------------------------
// qkv_mfma v3: 512 blocks x 4 waves, 16 rows/block, LDS-free.
// Wave w computes frags s in {w, w+4, w+8} (q,k,v cols w*16..+15), full K.
// A-frag per step: x[row0+n][kk*32+quad*8 .. +7] as two float4 + packed cvt.
// ---------------------------------------------------------------------------
#define SC2F 0.0450842200113808f // (1/32)*log2(e)

__global__ __launch_bounds__(256) void qkv_mfma(const float* __restrict__ x,
                                                const unsigned short* __restrict__ Wb,
                                                float* __restrict__ out,
                                                unsigned short* __restrict__ qb,
                                                unsigned short* __restrict__ kb,
                                                unsigned short* __restrict__ vT) {
    const int t    = threadIdx.x;
    const int wave = t >> 6, lane = t & 63;
    const int n    = lane & 15, quad = lane >> 4;
    const int row0 = blockIdx.x * 16;
    const int b    = row0 >> 11;

    const float* xr = x + (size_t)(row0 + n) * CC + quad * 8;

    f32x4 acc0 = (f32x4){0.f, 0.f, 0.f, 0.f};
    f32x4 acc1 = acc0, acc2 = acc0;

    const unsigned short* wp = Wb + (size_t)lane * 8;
    const size_t fs = (size_t)32 * 64 * 8; // frag-s stride

#pragma unroll 4
    for (int kk = 0; kk < 32; ++kk) {
        float4 fa = *(const float4*)(xr + kk * 32);
        float4 fb = *(const float4*)(xr + kk * 32 + 4);
        union { short8 s; uint4 u; } a;
        a.u.x = pkbf2(fa.x, fa.y);
        a.u.y = pkbf2(fa.z, fa.w);
        a.u.z = pkbf2(fb.x, fb.y);
        a.u.w = pkbf2(fb.z, fb.w);
        const unsigned short* wk_ = wp + (size_t)kk * 512;
        short8 b0 = *(const short8*)(wk_ + (size_t)(wave)     * fs);
        short8 b1 = *(const short8*)(wk_ + (size_t)(wave + 4) * fs);
        short8 b2 = *(const short8*)(wk_ + (size_t)(wave + 8) * fs);
        acc0 = __builtin_amdgcn_mfma_f32_16x16x32_bf16(a.s, b0, acc0, 0, 0, 0);
        acc1 = __builtin_amdgcn_mfma_f32_16x16x32_bf16(a.s, b1, acc1, 0, 0, 0);
        acc2 = __builtin_amdgcn_mfma_f32_16x16x32_bf16(a.s, b2, acc2, 0, 0, 0);
    }

    // epilogue (proven R11): C row = row0 + quad*4 + r, col h = wave*16 + n
    const int h = wave * 16 + n;
    const size_t g0 = (size_t)(row0 + quad * 4) * HH + h;

    unsigned int uq01 = pkbf2(acc0[0] * SC2F, acc0[1] * SC2F);
    unsigned int uq23 = pkbf2(acc0[2] * SC2F, acc0[3] * SC2F);
    unsigned int uk01 = pkbf2(acc1[0], acc1[1]);
    unsigned int uk23 = pkbf2(acc1[2], acc1[3]);
    qb[g0]          = (unsigned short)uq01;
    qb[g0 + HH]     = (unsigned short)(uq01 >> 16);
    qb[g0 + 2 * HH] = (unsigned short)uq23;
    qb[g0 + 3 * HH] = (unsigned short)(uq23 >> 16);
    kb[g0]          = (unsigned short)uk01;
    kb[g0 + HH]     = (unsigned short)(uk01 >> 16);
    kb[g0 + 2 * HH] = (unsigned short)uk23;
    kb[g0 + 3 * HH] = (unsigned short)(uk23 >> 16);
#pragma unroll
    for (int r = 0; r < 4; ++r) {
        out[NKV + g0 + (size_t)r * HH]     = acc1[r];
        out[2 * NKV + g0 + (size_t)r * HH] = acc2[r];
    }
    uint2 uv;
    uv.x = pkbf2(acc2[0], acc2[1]);
    uv.y = pkbf2(acc2[2], acc2[3]);
    *(uint2*)&vT[(size_t)(b * HH + h) * TT + (row0 & 2047) + quad * 4] = uv;
}

// ---------------------------------------------------------------------------
// attn_mfma v4 (R11 math, heavy-first order). Grid (128,4) x 4 waves; waves
// split K-tiles (kt = w mod 4). Static-max softmax (logits bounded), deferred
// l, plain cross-wave sum-merge.
// ---------------------------------------------------------------------------
__global__ __launch_bounds__(256) void attn_mfma(float* __restrict__ out,
                                                 const unsigned short* __restrict__ qb,
                                                 const unsigned short* __restrict__ kb,
                                                 const unsigned short* __restrict__ vT) {
    __shared__ __align__(16) unsigned short Ps[4][16][72]; // 9.2KB
    __shared__ float Lb[4][64][4];                         // 4KB
    __shared__ float Ob[4][64][16];                        // 16KB

    const int t    = threadIdx.x;
    const int wave = t >> 6, lane = t & 63;
    const int n    = lane & 15, quad = lane >> 4;
    const int qt   = 127 - blockIdx.x; // heavy-first: big nkt launches first
    const int b    = blockIdx.y;
    const int q0   = qt * 16;

    // Q A-fragments (pre-scaled by SC2): row = q0 + n
    const unsigned short* qr = qb + (size_t)(b * TT + q0 + n) * HH + quad * 8;
    short8 aq0 = *(const short8*)(qr);
    short8 aq1 = *(const short8*)(qr + 32);

    f32x4 oc[4];
#pragma unroll
    for (int d = 0; d < 4; ++d) oc[d] = (f32x4){0.f, 0.f, 0.f, 0.f};
    float l_[4] = {0.f, 0.f, 0.f, 0.f};

    const int nkt = (q0 >> 6) + 1;

    for (int kt = wave; kt < nkt; kt += 4) {
        const int j0 = kt * 64;

        // ---- scores (base-2 logits; q pre-scaled) ----
        f32x4 sc[4];
#pragma unroll
        for (int s = 0; s < 4; ++s) sc[s] = (f32x4){0.f, 0.f, 0.f, 0.f};
#pragma unroll
        for (int s = 0; s < 4; ++s) {
            const unsigned short* kr = kb + (size_t)(b * TT + j0 + s * 16 + n) * HH + quad * 8;
            short8 bk0 = *(const short8*)(kr);
            short8 bk1 = *(const short8*)(kr + 32);
            sc[s] = __builtin_amdgcn_mfma_f32_16x16x32_bf16(aq0, bk0, sc[s], 0, 0, 0);
            sc[s] = __builtin_amdgcn_mfma_f32_16x16x32_bf16(aq1, bk1, sc[s], 0, 0, 0);
        }

        // ---- p = exp2(sc); mask only on the single diagonal tile ----
        float p[4][4]; // [s][r]
        if (j0 + 63 <= q0) {
#pragma unroll
            for (int s = 0; s < 4; ++s)
#pragma unroll
                for (int r = 0; r < 4; ++r) {
                    float pe = exp2f(sc[s][r]);
                    p[s][r] = pe;
                    l_[r] += pe;
                }
        } else {
#pragma unroll
            for (int r = 0; r < 4; ++r) {
                const int qrow = q0 + quad * 4 + r;
#pragma unroll
                for (int s = 0; s < 4; ++s) {
                    int krow = j0 + s * 16 + n;
                    float pe = (krow <= qrow) ? exp2f(sc[s][r]) : 0.f;
                    p[s][r] = pe;
                    l_[r] += pe;
                }
            }
        }

        // ---- P: C-layout -> wave-private LDS -> A-layout (proven) ----
#pragma unroll
        for (int s = 0; s < 4; ++s) {
            unsigned int u01 = pkbf2(p[s][0], p[s][1]);
            unsigned int u23 = pkbf2(p[s][2], p[s][3]);
            Ps[wave][quad * 4 + 0][s * 16 + n] = (unsigned short)u01;
            Ps[wave][quad * 4 + 1][s * 16 + n] = (unsigned short)(u01 >> 16);
            Ps[wave][quad * 4 + 2][s * 16 + n] = (unsigned short)u23;
            Ps[wave][quad * 4 + 3][s * 16 + n] = (unsigned short)(u23 >> 16);
        }
        __asm__ volatile("s_waitcnt lgkmcnt(0)" ::: "memory");
        short8 ap0 = *(const short8*)&Ps[wave][n][quad * 8];
        short8 ap1 = *(const short8*)&Ps[wave][n][32 + quad * 8];

        // ---- O += P @ V ----
#pragma unroll
        for (int d = 0; d < 4; ++d) {
            const unsigned short* vr = vT + (size_t)(b * HH + d * 16 + n) * TT + j0 + quad * 8;
            short8 bv0 = *(const short8*)(vr);
            short8 bv1 = *(const short8*)(vr + 32);
            oc[d] = __builtin_amdgcn_mfma_f32_16x16x32_bf16(ap0, bv0, oc[d], 0, 0, 0);
            oc[d] = __builtin_amdgcn_mfma_f32_16x16x32_bf16(ap1, bv1, oc[d], 0, 0, 0);
        }
    }

    // ---- deferred l reduction across the 16 lanes sharing a row set ----
#pragma unroll
    for (int off = 1; off < 16; off <<= 1)
#pragma unroll
        for (int r = 0; r < 4; ++r)
            l_[r] += __shfl_xor(l_[r], off);

    // ---- cross-wave sum-merge ----
#pragma unroll
    for (int r = 0; r < 4; ++r) Lb[wave][lane][r] = l_[r];
#pragma unroll
    for (int d = 0; d < 4; ++d)
#pragma unroll
        for (int r = 0; r < 4; ++r)
            Ob[wave][lane][d * 4 + r] = oc[d][r];
    __syncthreads();

    if (wave == 0) {
#pragma unroll
        for (int r = 0; r < 4; ++r) {
            float ls = Lb[0][lane][r] + Lb[1][lane][r] + Lb[2][lane][r] + Lb[3][lane][r];
            const float inv = 1.f / ls;
#pragma unroll
            for (int d = 0; d < 4; ++d) {
                float o = Ob[0][lane][d * 4 + r] + Ob[1][lane][d * 4 + r] +
                          Ob[2][lane][d * 4 + r] + Ob[3][lane][d * 4 + r];
                out[(size_t)(b * TT + q0 + quad * 4 + r) * HH + d * 16 + n] = o * inv;
            }
        }
    }
}

// ---------------------------------------------------------------------------
extern "C" void kernel_launch(void* const* d_in, const int* in_sizes, int n_in,
                              void* d_out, int out_size, void* d_ws, size_t ws_size,
                              hipStream_t stream) {
    const float* x  = (const float*)d_in[0];
    const float* Wq = (const float*)d_in[1];
    const float* Wk = (const float*)d_in[2];
    const float* Wv = (const float*)d_in[3];
    float* out = (float*)d_out;

    char* ws = (char*)d_ws;
    unsigned short* Wb = (unsigned short*)(ws);              // 384 KB
    unsigned short* qb = (unsigned short*)(ws + (1u << 20)); // 1 MB
    unsigned short* kb = (unsigned short*)(ws + (2u << 20)); // 1 MB
    unsigned short* vT = (unsigned short*)(ws + (3u << 20)); // 1 MB

    prep_wb<<<768, 256, 0, stream>>>(Wq, Wk, Wv, Wb);
    qkv_mfma<<<512, 256, 0, stream>>>(x, Wb, out, qb, kb, vT);
    attn_mfma<<<dim3(128, 4), 256, 0, stream>>>(out, qb, kb, vT);
}

// Round 13
// 123.513 us; speedup vs baseline: 1.0582x; 1.0582x over previous
//
#include <hip/hip_runtime.h>
#include <hip/hip_bf16.h>
#include <stdint.h>

// Single attention head. B=4, T=2048, C=1024, H=64. FP32 in/out (proven).
// Outputs concat fp32: out[B,T,H], k[B,T,H], v[B,T,H]. scale = 1/32.
//
// R13 = R11 verbatim (R12's two changes both regressed: LDS-free qkv caused
// 4x x-read amplification; heavy-first was neutral-to-negative) + one
// micro-fix: the attn cross-wave merge epilogue runs on all 4 waves
// (wave w handles row-group r = w) instead of serializing on wave 0.
// ws (4 MB): [0) Wb 384KB; [1MB) qb; [2MB) kb; [3MB) vT (1MB each, bf16).

#define NB 4
#define TT 2048
#define CC 1024
#define HH 64
#define NKV (NB * TT * HH)

typedef __attribute__((ext_vector_type(8))) short short8; // 8 bf16 = 4 VGPRs
typedef __attribute__((ext_vector_type(4))) float f32x4;  // MFMA C/D

__device__ __forceinline__ unsigned short f2bf(float f) {
    union { float f; unsigned int i; } v;
    v.f = f;
    unsigned int r = v.i + 0x7fffu + ((v.i >> 16) & 1u); // RNE
    return (unsigned short)(r >> 16);
}
// packed RNE f32x2 -> bf16x2 (v_cvt_pk_bf16_f32 on gfx950)
__device__ __forceinline__ unsigned int pkbf2(float a, float b) {
    __hip_bfloat162 h = __float22bfloat162_rn(make_float2(a, b));
    union { __hip_bfloat162 h; unsigned int u; } c;
    c.h = h;
    return c.u;
}

// ---------------------------------------------------------------------------
// prep_wb (proven): Wb[((s*32+kk)*64 + l)*8 + j] =
// W_m[k = 32kk + (l>>4)*8 + j][h = (s&3)*16 + (l&15)], m = s>>2.
// ---------------------------------------------------------------------------
__global__ __launch_bounds__(256) void prep_wb(const float* __restrict__ Wq,
                                               const float* __restrict__ Wk,
                                               const float* __restrict__ Wv,
                                               unsigned short* __restrict__ Wb) {
    int gid = blockIdx.x * 256 + threadIdx.x; // 0 .. 196607
    int j  = gid & 7;
    int l  = (gid >> 3) & 63;
    int kk = (gid >> 9) & 31;
    int s  = gid >> 14;
    int k  = kk * 32 + (l >> 4) * 8 + j;
    int h  = (s & 3) * 16 + (l & 15);
    const float* W = (s >> 2) == 0 ? Wq : (s >> 2) == 1 ? Wk : Wv;
    Wb[gid] = f2bf(W[(size_t)k * HH + h]);
}

// ---------------------------------------------------------------------------
// qkv_mfma (R11-proven). 512 blocks x 4 waves, 16 rows/block; x staged to
// LDS bf16 (stride 1032: b128 frag reads 2-way bank-aliased = free).
// Wave w computes frags s in {w, w+4, w+8} (q,k,v cols w*16..+15), full K.
// ---------------------------------------------------------------------------
#define XSTR 1032
#define SC2F 0.0450842200113808f // (1/32)*log2(e)

__global__ __launch_bounds__(256) void qkv_mfma(const float* __restrict__ x,
                                                const unsigned short* __restrict__ Wb,
                                                float* __restrict__ out,
                                                unsigned short* __restrict__ qb,
                                                unsigned short* __restrict__ kb,
                                                unsigned short* __restrict__ vT) {
    __shared__ __align__(16) unsigned short xs[16 * XSTR]; // 33KB
    const int t    = threadIdx.x;
    const int wave = t >> 6, lane = t & 63;
    const int n    = lane & 15, quad = lane >> 4;
    const int row0 = blockIdx.x * 16;
    const int b    = row0 >> 11;

    // stage x tile (16 rows x 1024) fp32 -> bf16, packed converts
    for (int i = 0; i < 16; ++i) {
        float4 f = *(const float4*)(x + (size_t)(row0 + i) * CC + 4 * t);
        uint2 u;
        u.x = pkbf2(f.x, f.y);
        u.y = pkbf2(f.z, f.w);
        *(uint2*)&xs[i * XSTR + 4 * t] = u;
    }
    __syncthreads();

    f32x4 acc0 = (f32x4){0.f, 0.f, 0.f, 0.f};
    f32x4 acc1 = acc0, acc2 = acc0;

    const unsigned short* wp = Wb + (size_t)lane * 8;
    const size_t fs = (size_t)32 * 64 * 8; // frag-s stride

#pragma unroll 4
    for (int kk = 0; kk < 32; ++kk) {
        short8 a = *(const short8*)&xs[n * XSTR + kk * 32 + quad * 8];
        const unsigned short* wk_ = wp + (size_t)kk * 512;
        short8 b0 = *(const short8*)(wk_ + (size_t)(wave)     * fs);
        short8 b1 = *(const short8*)(wk_ + (size_t)(wave + 4) * fs);
        short8 b2 = *(const short8*)(wk_ + (size_t)(wave + 8) * fs);
        acc0 = __builtin_amdgcn_mfma_f32_16x16x32_bf16(a, b0, acc0, 0, 0, 0);
        acc1 = __builtin_amdgcn_mfma_f32_16x16x32_bf16(a, b1, acc1, 0, 0, 0);
        acc2 = __builtin_amdgcn_mfma_f32_16x16x32_bf16(a, b2, acc2, 0, 0, 0);
    }

    // epilogue: C row = row0 + quad*4 + r, col h = wave*16 + n
    const int h = wave * 16 + n;
    const size_t g0 = (size_t)(row0 + quad * 4) * HH + h;

    unsigned int uq01 = pkbf2(acc0[0] * SC2F, acc0[1] * SC2F);
    unsigned int uq23 = pkbf2(acc0[2] * SC2F, acc0[3] * SC2F);
    unsigned int uk01 = pkbf2(acc1[0], acc1[1]);
    unsigned int uk23 = pkbf2(acc1[2], acc1[3]);
    qb[g0]          = (unsigned short)uq01;
    qb[g0 + HH]     = (unsigned short)(uq01 >> 16);
    qb[g0 + 2 * HH] = (unsigned short)uq23;
    qb[g0 + 3 * HH] = (unsigned short)(uq23 >> 16);
    kb[g0]          = (unsigned short)uk01;
    kb[g0 + HH]     = (unsigned short)(uk01 >> 16);
    kb[g0 + 2 * HH] = (unsigned short)uk23;
    kb[g0 + 3 * HH] = (unsigned short)(uk23 >> 16);
#pragma unroll
    for (int r = 0; r < 4; ++r) {
        out[NKV + g0 + (size_t)r * HH]     = acc1[r];
        out[2 * NKV + g0 + (size_t)r * HH] = acc2[r];
    }
    uint2 uv;
    uv.x = pkbf2(acc2[0], acc2[1]);
    uv.y = pkbf2(acc2[2], acc2[3]);
    *(uint2*)&vT[(size_t)(b * HH + h) * TT + (row0 & 2047) + quad * 4] = uv;
}

// ---------------------------------------------------------------------------
// attn_mfma (R11-proven; merge epilogue spread across 4 waves).
// Grid (128 q-tiles, 4 batches) x 4 waves; waves split K-tiles (kt = w mod 4).
// Static-max softmax (logits bounded, q pre-scaled by SC2), deferred l,
// plain cross-wave sum-merge.
// ---------------------------------------------------------------------------
__global__ __launch_bounds__(256) void attn_mfma(float* __restrict__ out,
                                                 const unsigned short* __restrict__ qb,
                                                 const unsigned short* __restrict__ kb,
                                                 const unsigned short* __restrict__ vT) {
    __shared__ __align__(16) unsigned short Ps[4][16][72]; // 9.2KB
    __shared__ float Lb[4][64][4];                         // 4KB
    __shared__ float Ob[4][64][16];                        // 16KB

    const int t    = threadIdx.x;
    const int wave = t >> 6, lane = t & 63;
    const int n    = lane & 15, quad = lane >> 4;
    const int qt   = blockIdx.x, b = blockIdx.y;
    const int q0   = qt * 16;

    // Q A-fragments (pre-scaled by SC2): row = q0 + n
    const unsigned short* qr = qb + (size_t)(b * TT + q0 + n) * HH + quad * 8;
    short8 aq0 = *(const short8*)(qr);
    short8 aq1 = *(const short8*)(qr + 32);

    f32x4 oc[4];
#pragma unroll
    for (int d = 0; d < 4; ++d) oc[d] = (f32x4){0.f, 0.f, 0.f, 0.f};
    float l_[4] = {0.f, 0.f, 0.f, 0.f};

    const int nkt = (q0 >> 6) + 1;

    for (int kt = wave; kt < nkt; kt += 4) {
        const int j0 = kt * 64;

        // ---- scores (base-2 logits; q pre-scaled) ----
        f32x4 sc[4];
#pragma unroll
        for (int s = 0; s < 4; ++s) sc[s] = (f32x4){0.f, 0.f, 0.f, 0.f};
#pragma unroll
        for (int s = 0; s < 4; ++s) {
            const unsigned short* kr = kb + (size_t)(b * TT + j0 + s * 16 + n) * HH + quad * 8;
            short8 bk0 = *(const short8*)(kr);
            short8 bk1 = *(const short8*)(kr + 32);
            sc[s] = __builtin_amdgcn_mfma_f32_16x16x32_bf16(aq0, bk0, sc[s], 0, 0, 0);
            sc[s] = __builtin_amdgcn_mfma_f32_16x16x32_bf16(aq1, bk1, sc[s], 0, 0, 0);
        }

        // ---- p = exp2(sc); mask only on the single diagonal tile ----
        float p[4][4]; // [s][r]
        if (j0 + 63 <= q0) {
#pragma unroll
            for (int s = 0; s < 4; ++s)
#pragma unroll
                for (int r = 0; r < 4; ++r) {
                    float pe = exp2f(sc[s][r]);
                    p[s][r] = pe;
                    l_[r] += pe;
                }
        } else {
#pragma unroll
            for (int r = 0; r < 4; ++r) {
                const int qrow = q0 + quad * 4 + r;
#pragma unroll
                for (int s = 0; s < 4; ++s) {
                    int krow = j0 + s * 16 + n;
                    float pe = (krow <= qrow) ? exp2f(sc[s][r]) : 0.f;
                    p[s][r] = pe;
                    l_[r] += pe;
                }
            }
        }

        // ---- P: C-layout -> wave-private LDS -> A-layout (proven) ----
#pragma unroll
        for (int s = 0; s < 4; ++s) {
            unsigned int u01 = pkbf2(p[s][0], p[s][1]);
            unsigned int u23 = pkbf2(p[s][2], p[s][3]);
            Ps[wave][quad * 4 + 0][s * 16 + n] = (unsigned short)u01;
            Ps[wave][quad * 4 + 1][s * 16 + n] = (unsigned short)(u01 >> 16);
            Ps[wave][quad * 4 + 2][s * 16 + n] = (unsigned short)u23;
            Ps[wave][quad * 4 + 3][s * 16 + n] = (unsigned short)(u23 >> 16);
        }
        __asm__ volatile("s_waitcnt lgkmcnt(0)" ::: "memory");
        short8 ap0 = *(const short8*)&Ps[wave][n][quad * 8];
        short8 ap1 = *(const short8*)&Ps[wave][n][32 + quad * 8];

        // ---- O += P @ V ----
#pragma unroll
        for (int d = 0; d < 4; ++d) {
            const unsigned short* vr = vT + (size_t)(b * HH + d * 16 + n) * TT + j0 + quad * 8;
            short8 bv0 = *(const short8*)(vr);
            short8 bv1 = *(const short8*)(vr + 32);
            oc[d] = __builtin_amdgcn_mfma_f32_16x16x32_bf16(ap0, bv0, oc[d], 0, 0, 0);
            oc[d] = __builtin_amdgcn_mfma_f32_16x16x32_bf16(ap1, bv1, oc[d], 0, 0, 0);
        }
    }

    // ---- deferred l reduction across the 16 lanes sharing a row set ----
#pragma unroll
    for (int off = 1; off < 16; off <<= 1)
#pragma unroll
        for (int r = 0; r < 4; ++r)
            l_[r] += __shfl_xor(l_[r], off);

    // ---- cross-wave sum-merge (epilogue spread: wave w handles r = w) ----
#pragma unroll
    for (int r = 0; r < 4; ++r) Lb[wave][lane][r] = l_[r];
#pragma unroll
    for (int d = 0; d < 4; ++d)
#pragma unroll
        for (int r = 0; r < 4; ++r)
            Ob[wave][lane][d * 4 + r] = oc[d][r];
    __syncthreads();

    {
        const int r = wave; // each wave merges one row-group
        float ls = Lb[0][lane][r] + Lb[1][lane][r] + Lb[2][lane][r] + Lb[3][lane][r];
        const float inv = 1.f / ls;
#pragma unroll
        for (int d = 0; d < 4; ++d) {
            float o = Ob[0][lane][d * 4 + r] + Ob[1][lane][d * 4 + r] +
                      Ob[2][lane][d * 4 + r] + Ob[3][lane][d * 4 + r];
            out[(size_t)(b * TT + q0 + quad * 4 + r) * HH + d * 16 + n] = o * inv;
        }
    }
}

// ---------------------------------------------------------------------------
extern "C" void kernel_launch(void* const* d_in, const int* in_sizes, int n_in,
                              void* d_out, int out_size, void* d_ws, size_t ws_size,
                              hipStream_t stream) {
    const float* x  = (const float*)d_in[0];
    const float* Wq = (const float*)d_in[1];
    const float* Wk = (const float*)d_in[2];
    const float* Wv = (const float*)d_in[3];
    float* out = (float*)d_out;

    char* ws = (char*)d_ws;
    unsigned short* Wb = (unsigned short*)(ws);              // 384 KB
    unsigned short* qb = (unsigned short*)(ws + (1u << 20)); // 1 MB
    unsigned short* kb = (unsigned short*)(ws + (2u << 20)); // 1 MB
    unsigned short* vT = (unsigned short*)(ws + (3u << 20)); // 1 MB

    prep_wb<<<768, 256, 0, stream>>>(Wq, Wk, Wv, Wb);
    qkv_mfma<<<512, 256, 0, stream>>>(x, Wb, out, qb, kb, vT);
    attn_mfma<<<dim3(128, 4), 256, 0, stream>>>(out, qb, kb, vT);
}